// Round 21
// baseline (138.163 us; speedup 1.0000x reference)
//
#include <hip/hip_runtime.h>
#include <hip/hip_bf16.h>
#include <math.h>

typedef __attribute__((ext_vector_type(8)))  short short8;
typedef __attribute__((ext_vector_type(16))) float f32x16;

#define Bc    2
#define Hc    16
#define Lc    2048
#define Dc    128
#define QBLK  256
#define KBLK  128
#define LOG2E 1.4426950408889634f
#define SCALE 0.08838834764831845f           // 1/sqrt(128)
#define SCL2  (SCALE * LOG2E)                // log2-domain Q scale

// workspace layout  (order matters: main kernel's prefetch reads one tile past
// kb/vt ends -- must land in valid ws, never consumed)
#define KB_OFF   0u
#define KB_BYTES (32u * 2048u * 128u * 2u)
#define VT_OFF   (KB_OFF + KB_BYTES)
#define VT_BYTES (32u * 2048u * 128u * 2u)
#define MB_OFF   (VT_OFF + VT_BYTES)
#define MB_BYTES (2u * 2048u * 32u * 8u)

__device__ __forceinline__ unsigned pk2(float a, float b) {
    unsigned short ua = __builtin_bit_cast(unsigned short, __float2bfloat16(a));
    unsigned short ub = __builtin_bit_cast(unsigned short, __float2bfloat16(b));
    return (unsigned)ua | ((unsigned)ub << 16);
}
__device__ __forceinline__ unsigned short bf16b(float a) {
    return __builtin_bit_cast(unsigned short, __float2bfloat16(a));
}
__device__ __forceinline__ void gload_lds16(const void* g, void* l) {
    __builtin_amdgcn_global_load_lds(
        (const __attribute__((address_space(1))) unsigned int*)g,
        (__attribute__((address_space(3))) unsigned int*)l, 16, 0, 0);
}
__device__ __forceinline__ unsigned cvtpk(float lo, float hi) {
    unsigned r;
    asm("v_cvt_pk_bf16_f32 %0, %1, %2" : "=v"(r) : "v"(lo), "v"(hi));
    return r;
}

// ---- fused prepass: [0,4096) K->bf16 | [4096,6144) V relu+transpose | [6144,8192) mask pack ----
__global__ void prepass_kernel(const float* __restrict__ k, const float* __restrict__ v,
                               const int* __restrict__ mask,
                               unsigned short* __restrict__ kb, unsigned short* __restrict__ vt,
                               unsigned long long* __restrict__ mb) {
    __shared__ float t[32][132];
    int bid = blockIdx.x;
    int tid = threadIdx.x;
    if (bid < 4096) {
        size_t base = ((size_t)bid * 256 + tid) * 8;
        float4 f0 = *(const float4*)(k + base);
        float4 f1 = *(const float4*)(k + base + 4);
        uint4 w;
        w.x = pk2(f0.x, f0.y); w.y = pk2(f0.z, f0.w);
        w.z = pk2(f1.x, f1.y); w.w = pk2(f1.z, f1.w);
        *(uint4*)(kb + base) = w;
    } else if (bid < 6144) {
        int b2 = bid - 4096;
        int bh = b2 >> 6, l0 = (b2 & 63) * 32;
        const float* src = v + (size_t)bh * Lc * Dc + (size_t)l0 * Dc;
        unsigned short* dst = vt + (size_t)bh * Dc * Lc;
        #pragma unroll
        for (int i = 0; i < 4; ++i) {
            int c  = i * 256 + tid;
            int r  = c >> 5;
            int c4 = c & 31;
            float4 f = *(const float4*)(src + (size_t)r * Dc + c4 * 4);
            t[r][c4 * 4 + 0] = fmaxf(f.x, 0.f);
            t[r][c4 * 4 + 1] = fmaxf(f.y, 0.f);
            t[r][c4 * 4 + 2] = fmaxf(f.z, 0.f);
            t[r][c4 * 4 + 3] = fmaxf(f.w, 0.f);
        }
        __syncthreads();
        #pragma unroll
        for (int j = 0; j < 4; ++j) {
            int c  = j * 256 + tid;
            int d  = c >> 3;
            int c8 = c & 7;
            ushort4 o;
            o.x = bf16b(t[c8 * 4 + 0][d]);
            o.y = bf16b(t[c8 * 4 + 1][d]);
            o.z = bf16b(t[c8 * 4 + 2][d]);
            o.w = bf16b(t[c8 * 4 + 3][d]);
            *(ushort4*)(dst + (size_t)d * Lc + l0 + c8 * 4) = o;
        }
    } else {
        int m = bid - 6144;
        int wv = tid >> 6, lane = tid & 63;
        #pragma unroll
        for (int i = 0; i < 16; ++i) {
            int wid = m * 64 + wv * 16 + i;
            int b = wid >> 16, l = (wid >> 5) & 2047, ktw = wid & 31;
            int mm = mask[(((size_t)(b * 2048 + l)) << 11) + ktw * 64 + lane];
            unsigned long long bal = __ballot(mm != 0);
            if (lane == 0) mb[(((size_t)(b * 32 + ktw)) << 11) + l] = bal;
        }
    }
}

// ---- main: 8-wave single-block, KBLK=128 (2 passes/barrier), 128 KB LDS dbuf,
// launch_bounds(512,1) -> 256-VGPR cap (1 block/CU anyway), XCD-localized grid ----
__global__ __launch_bounds__(512, 1) void rev_attn_kernel(
    const float* __restrict__ q,
    const unsigned short* __restrict__ kb,
    const unsigned short* __restrict__ vt,
    const unsigned long long* __restrict__ mb,
    float* __restrict__ out)
{
    // LDS: Kbuf[2] @ 0/32768 (each: 2 x 16KB sub-tiles), Vbuf[2] @ 65536/98304 (same)
    __shared__ __align__(16) char smem[131072];

    const int tid  = threadIdx.x;
    const int w    = tid >> 6;          // 0..7
    const int lane = tid & 63;
    const int l31  = lane & 31;
    const int hi   = lane >> 5;
    const int bh   = blockIdx.x;        // flat-id % 8 == bh % 8 -> same-bh blocks share an XCD
    const int b    = bh >> 4;
    const int qb   = blockIdx.y * QBLK + w * 32;
    const int qrow = qb + l31;

    const float*              qp = q  + (size_t)bh * Lc * Dc;
    const unsigned short*     kp = kb + (size_t)bh * Lc * Dc;
    const unsigned short*     vp = vt + (size_t)bh * Dc * Lc;
    const unsigned long long* mp = mb + ((size_t)b << 16) + qrow;   // [32 ktw][2048 l]
    float*                    op = out + (size_t)bh * Lc * Dc;

    // ---- Q B-frags (log2-domain pre-scale): lane holds Q[qrow][c*16 + hi*8 + j] ----
    short8 qf[8];
    {
        const float* qr0 = qp + (size_t)qrow * Dc + hi * 8;
        #pragma unroll
        for (int c = 0; c < 8; ++c) {
            const float* src = qr0 + c * 16;
            #pragma unroll
            for (int j = 0; j < 8; ++j)
                qf[c][j] = (short)bf16b(src[j] * SCL2);
        }
    }

    // ---- compact hoisted LDS byte-offsets (row-B = +8192 literal; swz invariant) ----
    unsigned koff[8], voff[8];
    #pragma unroll
    for (int c = 0; c < 8; ++c)
        koff[c] = (unsigned)(l31 * 256 + ((((c << 1) | hi) ^ (l31 & 15)) << 4));
    #pragma unroll
    for (int hs = 0; hs < 2; ++hs)
        #pragma unroll
        for (int ks = 0; ks < 4; ++ks)
            voff[hs * 4 + ks] = (unsigned)(l31 * 256 +
                ((((hs << 3) | (ks << 1) | hi) ^ (l31 & 15)) << 4));

    // ---- loop-carried staging pointers (512 threads -> 2 K + 2 V chunks per sub-tile) ----
    const unsigned short *kp0, *kp1, *vp0, *vp1;
    {
        #define INITP(P, KP, VP) {                                   \
            int l   = (P) * 512 + tid;                               \
            int row = l >> 4, cl = l & 15;                           \
            int s_  = cl ^ (row & 15);                               \
            KP = kp + (size_t)row * Dc + s_ * 8;                     \
            int ds_ = row + ((s_ >> 3) << 6);                        \
            int ko_ = (s_ & 7) * 8;                                  \
            VP = vp + (size_t)ds_ * Lc + ko_;                        \
        }
        INITP(0, kp0, vp0) INITP(1, kp1, vp1)
        #undef INITP
    }

    f32x16 o0 = (f32x16)0.f, o1 = (f32x16)0.f, o2 = (f32x16)0.f, o3 = (f32x16)0.f;
    f32x16 lacc = (f32x16)0.f;          // denominator via MFMA(ones, P)
    short8 ones;
    #pragma unroll
    for (int j = 0; j < 8; ++j) ones[j] = (short)0x3F80;   // bf16 1.0

    // stage one 128-row K/V tile as two verified 64-row sub-tiles (8 loads/thread);
    // pointer advance past the end lands in adjacent ws regions (valid, unconsumed)
    #define STAGE(buf) do {                                                        \
        char* Kdst = smem + (buf) * 32768;                                         \
        char* Vdst = smem + 65536 + (buf) * 32768;                                 \
        gload_lds16(kp0, Kdst + tid * 16);                                         \
        gload_lds16(vp0, Vdst + tid * 16);                                         \
        gload_lds16(kp1, Kdst + 8192 + tid * 16);                                  \
        gload_lds16(vp1, Vdst + 8192 + tid * 16);                                  \
        kp0 += 64 * Dc; kp1 += 64 * Dc; vp0 += 64; vp1 += 64;                      \
        gload_lds16(kp0, Kdst + 16384 + tid * 16);                                 \
        gload_lds16(vp0, Vdst + 16384 + tid * 16);                                 \
        gload_lds16(kp1, Kdst + 24576 + tid * 16);                                 \
        gload_lds16(vp1, Vdst + 24576 + tid * 16);                                 \
        kp0 += 64 * Dc; kp1 += 64 * Dc; vp0 += 64; vp1 += 64;                      \
    } while (0)

    // slice: 8 elems of SV -> masked exp2 -> packed bf16 A-frag (cvt_pk + permlane32_swap)
    #define MK_SLICE(PA, SV, J0, CS0, MREG) do {                                   \
        float e0 = ((MREG >> (CS0 + 0)) & 1u)  ? __builtin_amdgcn_exp2f(SV[J0 + 0]) : 0.f; \
        float e1 = ((MREG >> (CS0 + 1)) & 1u)  ? __builtin_amdgcn_exp2f(SV[J0 + 1]) : 0.f; \
        float e2 = ((MREG >> (CS0 + 2)) & 1u)  ? __builtin_amdgcn_exp2f(SV[J0 + 2]) : 0.f; \
        float e3 = ((MREG >> (CS0 + 3)) & 1u)  ? __builtin_amdgcn_exp2f(SV[J0 + 3]) : 0.f; \
        float e4 = ((MREG >> (CS0 + 8)) & 1u)  ? __builtin_amdgcn_exp2f(SV[J0 + 4]) : 0.f; \
        float e5 = ((MREG >> (CS0 + 9)) & 1u)  ? __builtin_amdgcn_exp2f(SV[J0 + 5]) : 0.f; \
        float e6 = ((MREG >> (CS0 + 10)) & 1u) ? __builtin_amdgcn_exp2f(SV[J0 + 6]) : 0.f; \
        float e7 = ((MREG >> (CS0 + 11)) & 1u) ? __builtin_amdgcn_exp2f(SV[J0 + 7]) : 0.f; \
        unsigned a_ = cvtpk(e0, e1), a2_ = cvtpk(e2, e3);                          \
        unsigned b_ = cvtpk(e4, e5), b2_ = cvtpk(e6, e7);                          \
        asm volatile("v_permlane32_swap_b32 %0, %1" : "+v"(a_),  "+v"(b_));        \
        asm volatile("v_permlane32_swap_b32 %0, %1" : "+v"(a2_), "+v"(b2_));       \
        union { unsigned u[4]; short8 v8; } tu_;                                   \
        tu_.u[0] = a_; tu_.u[1] = a2_; tu_.u[2] = b_; tu_.u[3] = b2_;              \
        PA = tu_.v8;                                                               \
    } while (0)

    // PV for one k-slice: lacc + 4 d-tiles (offsets hoisted; +8192 = row-B literal)
    #define PV_SLICE(PA, KS, VB) do {                                              \
        __builtin_amdgcn_s_setprio(1);                                             \
        lacc = __builtin_amdgcn_mfma_f32_32x32x16_bf16(ones, PA, lacc, 0, 0, 0);   \
        short8 vfa = *(const short8*)((VB) + voff[KS]);                            \
        o0 = __builtin_amdgcn_mfma_f32_32x32x16_bf16(vfa, PA, o0, 0, 0, 0);        \
        short8 vfb = *(const short8*)((VB) + voff[KS] + 8192);                     \
        o1 = __builtin_amdgcn_mfma_f32_32x32x16_bf16(vfb, PA, o1, 0, 0, 0);        \
        short8 vfc = *(const short8*)((VB) + voff[4 + KS]);                        \
        o2 = __builtin_amdgcn_mfma_f32_32x32x16_bf16(vfc, PA, o2, 0, 0, 0);        \
        short8 vfd = *(const short8*)((VB) + voff[4 + KS] + 8192);                 \
        o3 = __builtin_amdgcn_mfma_f32_32x32x16_bf16(vfd, PA, o3, 0, 0, 0);        \
        __builtin_amdgcn_s_setprio(0);                                             \
    } while (0)

    // one 64-row compute pass: QK^T + sm-split PV against sub-tile at (KB, VB)
    #define PASS(KB, VB, MW) do {                                                  \
        f32x16 s0 = (f32x16)0.f, s1 = (f32x16)0.f;                                 \
        __builtin_amdgcn_s_setprio(1);                                             \
        _Pragma("unroll")                                                          \
        for (int c = 0; c < 8; ++c) {                                              \
            short8 kf0 = *(const short8*)((KB) + koff[c]);                         \
            s0 = __builtin_amdgcn_mfma_f32_32x32x16_bf16(kf0, qf[c], s0, 0, 0, 0); \
            short8 kf1 = *(const short8*)((KB) + koff[c] + 8192);                  \
            s1 = __builtin_amdgcn_mfma_f32_32x32x16_bf16(kf1, qf[c], s1, 0, 0, 0); \
        }                                                                          \
        __builtin_amdgcn_s_setprio(0);                                             \
        unsigned m0 = ((unsigned)((MW) & 0xffffffffull)) >> (4 * hi);              \
        unsigned m1 = ((unsigned)((MW) >> 32)) >> (4 * hi);                        \
        short8 pa;                                                                 \
        MK_SLICE(pa, s0, 0, 0,  m0);  PV_SLICE(pa, 0, VB);                         \
        MK_SLICE(pa, s0, 8, 16, m0);  PV_SLICE(pa, 1, VB);                         \
        MK_SLICE(pa, s1, 0, 0,  m1);  PV_SLICE(pa, 2, VB);                         \
        MK_SLICE(pa, s1, 8, 16, m1);  PV_SLICE(pa, 3, VB);                         \
    } while (0)

    int cur = 0;
    STAGE(0);
    unsigned long long mwa = mp[0];                  // ktw 0
    unsigned long long mwb = mp[(size_t)1 << 11];    // ktw 1
    asm volatile("s_waitcnt vmcnt(0)" ::: "memory");
    __builtin_amdgcn_s_barrier();
    __builtin_amdgcn_sched_barrier(0);

    for (int kt = 0; kt < Lc; kt += KBLK) {
        // prefetch next 128-tile (8 loads) + next 2 mask words (clamped; harmless re-read)
        STAGE(cur ^ 1);
        int t0 = (kt >> 6) + 2; if (t0 > 31) t0 = 31;
        int t1 = (kt >> 6) + 3; if (t1 > 31) t1 = 31;
        unsigned long long mwa_n = mp[(size_t)t0 << 11];
        unsigned long long mwb_n = mp[(size_t)t1 << 11];

        // cur buffer + masks ready: prior iter's 10 loads drained; 8+2 newest remain
        asm volatile("s_waitcnt vmcnt(10)" ::: "memory");
        __builtin_amdgcn_s_barrier();
        __builtin_amdgcn_sched_barrier(0);

        const char* Kb = smem + cur * 32768;
        const char* Vb = smem + 65536 + cur * 32768;

        PASS(Kb,         Vb,         mwa);   // k rows [kt, kt+64)
        PASS(Kb + 16384, Vb + 16384, mwb);   // k rows [kt+64, kt+128)

        // all reads of cur done before next iter's STAGE overwrites it
        asm volatile("" ::: "memory");
        __builtin_amdgcn_s_barrier();
        __builtin_amdgcn_sched_barrier(0);
        mwa = mwa_n; mwb = mwb_n;
        cur ^= 1;
    }

    // ---- epilogue: O^T -> LDS transpose -> coalesced float4 stores ----
    __syncthreads();
    float inv = 1.0f / lacc[0];         // all regs identical (A = ones); col=q=l31
    float* scr = (float*)(smem + w * 4608);
    const int qq = lane >> 1;
    const int dh = (lane & 1) * 16;
    #pragma unroll
    for (int dt = 0; dt < 4; ++dt) {
        const f32x16& oo = (dt == 0) ? o0 : (dt == 1) ? o1 : (dt == 2) ? o2 : o3;
        #pragma unroll
        for (int r = 0; r < 16; ++r) {
            int drow = (r & 3) + 8 * (r >> 2) + 4 * hi;
            scr[drow * 36 + l31] = oo[r] * inv;
        }
        asm volatile("s_waitcnt lgkmcnt(0)" ::: "memory");
        __builtin_amdgcn_sched_barrier(0);
        float t[16];
        #pragma unroll
        for (int c2 = 0; c2 < 16; ++c2)
            t[c2] = scr[(dh + c2) * 36 + qq];
        asm volatile("s_waitcnt lgkmcnt(0)" ::: "memory");
        __builtin_amdgcn_sched_barrier(0);
        float* od = op + (size_t)(qb + qq) * Dc + dt * 32 + dh;
        #pragma unroll
        for (int c2 = 0; c2 < 4; ++c2) {
            float4 f4; f4.x = t[c2*4]; f4.y = t[c2*4+1]; f4.z = t[c2*4+2]; f4.w = t[c2*4+3];
            *(float4*)(od + c2 * 4) = f4;
        }
    }
}

extern "C" void kernel_launch(void* const* d_in, const int* in_sizes, int n_in,
                              void* d_out, int out_size, void* d_ws, size_t ws_size,
                              hipStream_t stream) {
    const float* q    = (const float*)d_in[0];
    const float* k    = (const float*)d_in[1];
    const float* v    = (const float*)d_in[2];
    const int*   mask = (const int*)d_in[3];
    float*       out  = (float*)d_out;

    char* ws = (char*)d_ws;
    unsigned short*     kb  = (unsigned short*)(ws + KB_OFF);
    unsigned short*     vt  = (unsigned short*)(ws + VT_OFF);
    unsigned long long* mbp = (unsigned long long*)(ws + MB_OFF);

    hipLaunchKernelGGL(prepass_kernel, dim3(8192), dim3(256), 0, stream, k, v, mask, kb, vt, mbp);
    // grid (bh, qx): flat id % 8 == bh % 8 -> same-bh q-blocks share one XCD's L2
    hipLaunchKernelGGL(rev_attn_kernel, dim3(Bc * Hc, Lc / QBLK), dim3(512), 0, stream,
                       q, kb, vt, mbp, out);
}

// Round 22
// 107.925 us; speedup vs baseline: 1.2802x; 1.2802x over previous
//
#include <hip/hip_runtime.h>
#include <hip/hip_bf16.h>
#include <math.h>

typedef __attribute__((ext_vector_type(8)))  short short8;
typedef __attribute__((ext_vector_type(16))) float f32x16;

#define Bc    2
#define Hc    16
#define Lc    2048
#define Dc    128
#define QBLK  256
#define KBLK  64
#define LOG2E 1.4426950408889634f
#define SCALE 0.08838834764831845f           // 1/sqrt(128)
#define SCL2  (SCALE * LOG2E)                // log2-domain Q scale

// workspace layout  (order matters: main kernel's prefetch reads one tile past
// kb/vt ends -- must land in valid ws, never consumed)
#define KB_OFF   0u
#define KB_BYTES (32u * 2048u * 128u * 2u)
#define VT_OFF   (KB_OFF + KB_BYTES)
#define VT_BYTES (32u * 2048u * 128u * 2u)
#define MB_OFF   (VT_OFF + VT_BYTES)
#define MB_BYTES (2u * 2048u * 32u * 8u)

__device__ __forceinline__ unsigned pk2(float a, float b) {
    unsigned short ua = __builtin_bit_cast(unsigned short, __float2bfloat16(a));
    unsigned short ub = __builtin_bit_cast(unsigned short, __float2bfloat16(b));
    return (unsigned)ua | ((unsigned)ub << 16);
}
__device__ __forceinline__ unsigned short bf16b(float a) {
    return __builtin_bit_cast(unsigned short, __float2bfloat16(a));
}
__device__ __forceinline__ void gload_lds16(const void* g, void* l) {
    __builtin_amdgcn_global_load_lds(
        (const __attribute__((address_space(1))) unsigned int*)g,
        (__attribute__((address_space(3))) unsigned int*)l, 16, 0, 0);
}
__device__ __forceinline__ unsigned cvtpk(float lo, float hi) {
    unsigned r;
    asm("v_cvt_pk_bf16_f32 %0, %1, %2" : "=v"(r) : "v"(lo), "v"(hi));
    return r;
}

// ---- fused prepass: [0,4096) K->bf16 | [4096,6144) V relu+transpose | [6144,8192) mask pack ----
__global__ void prepass_kernel(const float* __restrict__ k, const float* __restrict__ v,
                               const int* __restrict__ mask,
                               unsigned short* __restrict__ kb, unsigned short* __restrict__ vt,
                               unsigned long long* __restrict__ mb) {
    __shared__ float t[32][132];
    int bid = blockIdx.x;
    int tid = threadIdx.x;
    if (bid < 4096) {
        size_t base = ((size_t)bid * 256 + tid) * 8;
        float4 f0 = *(const float4*)(k + base);
        float4 f1 = *(const float4*)(k + base + 4);
        uint4 w;
        w.x = pk2(f0.x, f0.y); w.y = pk2(f0.z, f0.w);
        w.z = pk2(f1.x, f1.y); w.w = pk2(f1.z, f1.w);
        *(uint4*)(kb + base) = w;
    } else if (bid < 6144) {
        int b2 = bid - 4096;
        int bh = b2 >> 6, l0 = (b2 & 63) * 32;
        const float* src = v + (size_t)bh * Lc * Dc + (size_t)l0 * Dc;
        unsigned short* dst = vt + (size_t)bh * Dc * Lc;
        #pragma unroll
        for (int i = 0; i < 4; ++i) {
            int c  = i * 256 + tid;
            int r  = c >> 5;
            int c4 = c & 31;
            float4 f = *(const float4*)(src + (size_t)r * Dc + c4 * 4);
            t[r][c4 * 4 + 0] = fmaxf(f.x, 0.f);
            t[r][c4 * 4 + 1] = fmaxf(f.y, 0.f);
            t[r][c4 * 4 + 2] = fmaxf(f.z, 0.f);
            t[r][c4 * 4 + 3] = fmaxf(f.w, 0.f);
        }
        __syncthreads();
        #pragma unroll
        for (int j = 0; j < 4; ++j) {
            int c  = j * 256 + tid;
            int d  = c >> 3;
            int c8 = c & 7;
            ushort4 o;
            o.x = bf16b(t[c8 * 4 + 0][d]);
            o.y = bf16b(t[c8 * 4 + 1][d]);
            o.z = bf16b(t[c8 * 4 + 2][d]);
            o.w = bf16b(t[c8 * 4 + 3][d]);
            *(ushort4*)(dst + (size_t)d * Lc + l0 + c8 * 4) = o;
        }
    } else {
        int m = bid - 6144;
        int wv = tid >> 6, lane = tid & 63;
        #pragma unroll
        for (int i = 0; i < 16; ++i) {
            int wid = m * 64 + wv * 16 + i;
            int b = wid >> 16, l = (wid >> 5) & 2047, ktw = wid & 31;
            int mm = mask[(((size_t)(b * 2048 + l)) << 11) + ktw * 64 + lane];
            unsigned long long bal = __ballot(mm != 0);
            if (lane == 0) mb[(((size_t)(b * 32 + ktw)) << 11) + l] = bal;
        }
    }
}

// ---- main: 8-wave single-block, XCD-L2-localized grid (x=bh -> all q-blocks of a
// bh land on one XCD's L2; 4 bh panels x 1 MB = 4 MB = L2 size) ----
__global__ __launch_bounds__(512, 2) void rev_attn_kernel(
    const float* __restrict__ q,
    const unsigned short* __restrict__ kb,
    const unsigned short* __restrict__ vt,
    const unsigned long long* __restrict__ mb,
    float* __restrict__ out)
{
    // LDS: Kbuf[2] @ 0/16384, Vbuf[2] @ 32768/49152; epilogue scratch aliases base
    __shared__ __align__(16) char smem[65536];

    const int tid  = threadIdx.x;
    const int w    = tid >> 6;          // 0..7
    const int lane = tid & 63;
    const int l31  = lane & 31;
    const int hi   = lane >> 5;
    const int bh   = blockIdx.x;        // flat-id % 8 == bh % 8 -> same-bh blocks share an XCD
    const int b    = bh >> 4;
    const int qb   = blockIdx.y * QBLK + w * 32;
    const int qrow = qb + l31;

    const float*              qp = q  + (size_t)bh * Lc * Dc;
    const unsigned short*     kp = kb + (size_t)bh * Lc * Dc;
    const unsigned short*     vp = vt + (size_t)bh * Dc * Lc;
    const unsigned long long* mp = mb + ((size_t)b << 16) + qrow;   // [32 ktw][2048 l]
    float*                    op = out + (size_t)bh * Lc * Dc;

    // ---- Q B-frags (log2-domain pre-scale): lane holds Q[qrow][c*16 + hi*8 + j] ----
    short8 qf[8];
    {
        const float* qr0 = qp + (size_t)qrow * Dc + hi * 8;
        #pragma unroll
        for (int c = 0; c < 8; ++c) {
            const float* src = qr0 + c * 16;
            #pragma unroll
            for (int j = 0; j < 8; ++j)
                qf[c][j] = (short)bf16b(src[j] * SCL2);
        }
    }

    // ---- compact hoisted LDS byte-offsets (row-B = +8192 literal; swz invariant) ----
    unsigned koff[8], voff[8];
    #pragma unroll
    for (int c = 0; c < 8; ++c)
        koff[c] = (unsigned)(l31 * 256 + ((((c << 1) | hi) ^ (l31 & 15)) << 4));
    #pragma unroll
    for (int hs = 0; hs < 2; ++hs)
        #pragma unroll
        for (int ks = 0; ks < 4; ++ks)
            voff[hs * 4 + ks] = (unsigned)(l31 * 256 +
                ((((hs << 3) | (ks << 1) | hi) ^ (l31 & 15)) << 4));

    // ---- loop-carried staging pointers (512 threads -> 2 K + 2 V chunks each) ----
    const unsigned short *kp0, *kp1, *vp0, *vp1;
    {
        #define INITP(P, KP, VP) {                                   \
            int l   = (P) * 512 + tid;                               \
            int row = l >> 4, cl = l & 15;                           \
            int s_  = cl ^ (row & 15);                               \
            KP = kp + (size_t)row * Dc + s_ * 8;                     \
            int ds_ = row + ((s_ >> 3) << 6);                        \
            int ko_ = (s_ & 7) * 8;                                  \
            VP = vp + (size_t)ds_ * Lc + ko_;                        \
        }
        INITP(0, kp0, vp0) INITP(1, kp1, vp1)
        #undef INITP
    }

    f32x16 o0 = (f32x16)0.f, o1 = (f32x16)0.f, o2 = (f32x16)0.f, o3 = (f32x16)0.f;
    f32x16 lacc = (f32x16)0.f;          // denominator via MFMA(ones, P)
    short8 ones;
    #pragma unroll
    for (int j = 0; j < 8; ++j) ones[j] = (short)0x3F80;   // bf16 1.0

    // stage current pointers into buf, then advance (last advance reads 1 tile OOB
    // into the adjacent ws region -- valid memory, never consumed)
    #define STAGE(buf) do {                                                        \
        char* Kdst = smem + (buf) * 16384;                                         \
        char* Vdst = smem + 32768 + (buf) * 16384;                                 \
        gload_lds16(kp0, Kdst + tid * 16);                                         \
        gload_lds16(vp0, Vdst + tid * 16);                                         \
        gload_lds16(kp1, Kdst + 8192 + tid * 16);                                  \
        gload_lds16(vp1, Vdst + 8192 + tid * 16);                                  \
        kp0 += KBLK * Dc; kp1 += KBLK * Dc;                                        \
        vp0 += KBLK;      vp1 += KBLK;                                             \
    } while (0)

    // slice: 8 elems of SV -> masked exp2 -> packed bf16 A-frag (cvt_pk + permlane32_swap)
    #define MK_SLICE(PA, SV, J0, CS0, MREG) do {                                   \
        float e0 = ((MREG >> (CS0 + 0)) & 1u)  ? __builtin_amdgcn_exp2f(SV[J0 + 0]) : 0.f; \
        float e1 = ((MREG >> (CS0 + 1)) & 1u)  ? __builtin_amdgcn_exp2f(SV[J0 + 1]) : 0.f; \
        float e2 = ((MREG >> (CS0 + 2)) & 1u)  ? __builtin_amdgcn_exp2f(SV[J0 + 2]) : 0.f; \
        float e3 = ((MREG >> (CS0 + 3)) & 1u)  ? __builtin_amdgcn_exp2f(SV[J0 + 3]) : 0.f; \
        float e4 = ((MREG >> (CS0 + 8)) & 1u)  ? __builtin_amdgcn_exp2f(SV[J0 + 4]) : 0.f; \
        float e5 = ((MREG >> (CS0 + 9)) & 1u)  ? __builtin_amdgcn_exp2f(SV[J0 + 5]) : 0.f; \
        float e6 = ((MREG >> (CS0 + 10)) & 1u) ? __builtin_amdgcn_exp2f(SV[J0 + 6]) : 0.f; \
        float e7 = ((MREG >> (CS0 + 11)) & 1u) ? __builtin_amdgcn_exp2f(SV[J0 + 7]) : 0.f; \
        unsigned a_ = cvtpk(e0, e1), a2_ = cvtpk(e2, e3);                          \
        unsigned b_ = cvtpk(e4, e5), b2_ = cvtpk(e6, e7);                          \
        asm volatile("v_permlane32_swap_b32 %0, %1" : "+v"(a_),  "+v"(b_));        \
        asm volatile("v_permlane32_swap_b32 %0, %1" : "+v"(a2_), "+v"(b2_));       \
        union { unsigned u[4]; short8 v8; } tu_;                                   \
        tu_.u[0] = a_; tu_.u[1] = a2_; tu_.u[2] = b_; tu_.u[3] = b2_;              \
        PA = tu_.v8;                                                               \
    } while (0)

    // PV for one k-slice: lacc + 4 d-tiles (offsets hoisted; +8192 = row-B literal)
    #define PV_SLICE(PA, KS) do {                                                  \
        __builtin_amdgcn_s_setprio(1);                                             \
        lacc = __builtin_amdgcn_mfma_f32_32x32x16_bf16(ones, PA, lacc, 0, 0, 0);   \
        short8 vfa = *(const short8*)(Vb + voff[KS]);                              \
        o0 = __builtin_amdgcn_mfma_f32_32x32x16_bf16(vfa, PA, o0, 0, 0, 0);        \
        short8 vfb = *(const short8*)(Vb + voff[KS] + 8192);                       \
        o1 = __builtin_amdgcn_mfma_f32_32x32x16_bf16(vfb, PA, o1, 0, 0, 0);        \
        short8 vfc = *(const short8*)(Vb + voff[4 + KS]);                          \
        o2 = __builtin_amdgcn_mfma_f32_32x32x16_bf16(vfc, PA, o2, 0, 0, 0);        \
        short8 vfd = *(const short8*)(Vb + voff[4 + KS] + 8192);                   \
        o3 = __builtin_amdgcn_mfma_f32_32x32x16_bf16(vfd, PA, o3, 0, 0, 0);        \
        __builtin_amdgcn_s_setprio(0);                                             \
    } while (0)

    int cur = 0;
    STAGE(0);
    unsigned long long mw_cur = mp[0];       // tile 0 mask word (prologue prefetch)
    asm volatile("s_waitcnt vmcnt(0)" ::: "memory");
    __builtin_amdgcn_s_barrier();
    __builtin_amdgcn_sched_barrier(0);

    for (int kt = 0; kt < Lc; kt += KBLK) {
        // prefetch next tile (pointers already advanced; final iter reads OOB-safe)
        STAGE(cur ^ 1);
        // prefetch next mask word (clamped at last tile -- harmless re-read)
        int tn = (kt >> 6) + 1; if (tn > 31) tn = 31;
        unsigned long long mw_next = mp[(size_t)tn << 11];

        // cur buffer + mw_cur ready: prior-iter 5 loads drained; 4 new + 1 mask remain
        asm volatile("s_waitcnt vmcnt(5)" ::: "memory");
        __builtin_amdgcn_s_barrier();
        __builtin_amdgcn_sched_barrier(0);

        const char* Kb = smem + cur * 16384;
        const char* Vb = smem + 32768 + cur * 16384;

        // ---- QK^T (swapped): S^T[k][q], col=q=l31 ----
        f32x16 s0 = (f32x16)0.f, s1 = (f32x16)0.f;
        __builtin_amdgcn_s_setprio(1);
        #pragma unroll
        for (int c = 0; c < 8; ++c) {
            short8 kf0 = *(const short8*)(Kb + koff[c]);
            s0 = __builtin_amdgcn_mfma_f32_32x32x16_bf16(kf0, qf[c], s0, 0, 0, 0);
            short8 kf1 = *(const short8*)(Kb + koff[c] + 8192);
            s1 = __builtin_amdgcn_mfma_f32_32x32x16_bf16(kf1, qf[c], s1, 0, 0, 0);
        }
        __builtin_amdgcn_s_setprio(0);

        unsigned m0 = ((unsigned)(mw_cur & 0xffffffffull)) >> (4 * hi);
        unsigned m1 = ((unsigned)(mw_cur >> 32)) >> (4 * hi);

        // ---- sm-split: per k-slice {softmax 8 elems} then {5 MFMAs} ----
        short8 pa;
        MK_SLICE(pa, s0, 0, 0,  m0);  PV_SLICE(pa, 0);
        MK_SLICE(pa, s0, 8, 16, m0);  PV_SLICE(pa, 1);
        MK_SLICE(pa, s1, 0, 0,  m1);  PV_SLICE(pa, 2);
        MK_SLICE(pa, s1, 8, 16, m1);  PV_SLICE(pa, 3);

        // all reads of cur done before next iter's STAGE overwrites it
        asm volatile("" ::: "memory");
        __builtin_amdgcn_s_barrier();
        __builtin_amdgcn_sched_barrier(0);
        mw_cur = mw_next;
        cur ^= 1;
    }

    // ---- epilogue: O^T -> LDS transpose -> coalesced float4 stores ----
    __syncthreads();
    float inv = 1.0f / lacc[0];         // all regs identical (A = ones); col=q=l31
    float* scr = (float*)(smem + w * 4608);
    const int qq = lane >> 1;
    const int dh = (lane & 1) * 16;
    #pragma unroll
    for (int dt = 0; dt < 4; ++dt) {
        const f32x16& oo = (dt == 0) ? o0 : (dt == 1) ? o1 : (dt == 2) ? o2 : o3;
        #pragma unroll
        for (int r = 0; r < 16; ++r) {
            int drow = (r & 3) + 8 * (r >> 2) + 4 * hi;
            scr[drow * 36 + l31] = oo[r] * inv;
        }
        asm volatile("s_waitcnt lgkmcnt(0)" ::: "memory");
        __builtin_amdgcn_sched_barrier(0);
        float t[16];
        #pragma unroll
        for (int c2 = 0; c2 < 16; ++c2)
            t[c2] = scr[(dh + c2) * 36 + qq];
        asm volatile("s_waitcnt lgkmcnt(0)" ::: "memory");
        __builtin_amdgcn_sched_barrier(0);
        float* od = op + (size_t)(qb + qq) * Dc + dt * 32 + dh;
        #pragma unroll
        for (int c2 = 0; c2 < 4; ++c2) {
            float4 f4; f4.x = t[c2*4]; f4.y = t[c2*4+1]; f4.z = t[c2*4+2]; f4.w = t[c2*4+3];
            *(float4*)(od + c2 * 4) = f4;
        }
    }
}

extern "C" void kernel_launch(void* const* d_in, const int* in_sizes, int n_in,
                              void* d_out, int out_size, void* d_ws, size_t ws_size,
                              hipStream_t stream) {
    const float* q    = (const float*)d_in[0];
    const float* k    = (const float*)d_in[1];
    const float* v    = (const float*)d_in[2];
    const int*   mask = (const int*)d_in[3];
    float*       out  = (float*)d_out;

    char* ws = (char*)d_ws;
    unsigned short*     kb  = (unsigned short*)(ws + KB_OFF);
    unsigned short*     vt  = (unsigned short*)(ws + VT_OFF);
    unsigned long long* mbp = (unsigned long long*)(ws + MB_OFF);

    hipLaunchKernelGGL(prepass_kernel, dim3(8192), dim3(256), 0, stream, k, v, mask, kb, vt, mbp);
    // grid (bh, qx): flat id % 8 == bh % 8 -> same-bh q-blocks share one XCD's L2
    hipLaunchKernelGGL(rev_attn_kernel, dim3(Bc * Hc, Lc / QBLK), dim3(512), 0, stream,
                       q, kb, vt, mbp, out);
}

// Round 24
// 107.142 us; speedup vs baseline: 1.2895x; 1.0073x over previous
//
#include <hip/hip_runtime.h>
#include <hip/hip_bf16.h>
#include <math.h>

typedef __attribute__((ext_vector_type(8)))  short short8;
typedef __attribute__((ext_vector_type(16))) float f32x16;

#define Bc    2
#define Hc    16
#define Lc    2048
#define Dc    128
#define QBLK  256
#define KBLK  64
#define LOG2E 1.4426950408889634f
#define SCALE 0.08838834764831845f           // 1/sqrt(128)
#define SCL2  (SCALE * LOG2E)                // log2-domain Q scale

// workspace layout  (order matters: main kernel's prefetch reads up to two tiles
// past kb/vt ends -- must land in valid ws, never consumed)
#define KB_OFF   0u
#define KB_BYTES (32u * 2048u * 128u * 2u)
#define VT_OFF   (KB_OFF + KB_BYTES)
#define VT_BYTES (32u * 2048u * 128u * 2u)
#define MB_OFF   (VT_OFF + VT_BYTES)
#define MB_BYTES (2u * 2048u * 32u * 8u)

__device__ __forceinline__ unsigned pk2(float a, float b) {
    unsigned short ua = __builtin_bit_cast(unsigned short, __float2bfloat16(a));
    unsigned short ub = __builtin_bit_cast(unsigned short, __float2bfloat16(b));
    return (unsigned)ua | ((unsigned)ub << 16);
}
__device__ __forceinline__ unsigned short bf16b(float a) {
    return __builtin_bit_cast(unsigned short, __float2bfloat16(a));
}
__device__ __forceinline__ void gload_lds16(const void* g, void* l) {
    __builtin_amdgcn_global_load_lds(
        (const __attribute__((address_space(1))) unsigned int*)g,
        (__attribute__((address_space(3))) unsigned int*)l, 16, 0, 0);
}
__device__ __forceinline__ unsigned cvtpk(float lo, float hi) {
    unsigned r;
    asm("v_cvt_pk_bf16_f32 %0, %1, %2" : "=v"(r) : "v"(lo), "v"(hi));
    return r;
}

// ---- fused prepass: [0,4096) K->bf16 | [4096,6144) V relu+transpose | [6144,8192) mask pack ----
__global__ void prepass_kernel(const float* __restrict__ k, const float* __restrict__ v,
                               const int* __restrict__ mask,
                               unsigned short* __restrict__ kb, unsigned short* __restrict__ vt,
                               unsigned long long* __restrict__ mb) {
    __shared__ float t[32][132];
    int bid = blockIdx.x;
    int tid = threadIdx.x;
    if (bid < 4096) {
        size_t base = ((size_t)bid * 256 + tid) * 8;
        float4 f0 = *(const float4*)(k + base);
        float4 f1 = *(const float4*)(k + base + 4);
        uint4 w;
        w.x = pk2(f0.x, f0.y); w.y = pk2(f0.z, f0.w);
        w.z = pk2(f1.x, f1.y); w.w = pk2(f1.z, f1.w);
        *(uint4*)(kb + base) = w;
    } else if (bid < 6144) {
        int b2 = bid - 4096;
        int bh = b2 >> 6, l0 = (b2 & 63) * 32;
        const float* src = v + (size_t)bh * Lc * Dc + (size_t)l0 * Dc;
        unsigned short* dst = vt + (size_t)bh * Dc * Lc;
        #pragma unroll
        for (int i = 0; i < 4; ++i) {
            int c  = i * 256 + tid;
            int r  = c >> 5;
            int c4 = c & 31;
            float4 f = *(const float4*)(src + (size_t)r * Dc + c4 * 4);
            t[r][c4 * 4 + 0] = fmaxf(f.x, 0.f);
            t[r][c4 * 4 + 1] = fmaxf(f.y, 0.f);
            t[r][c4 * 4 + 2] = fmaxf(f.z, 0.f);
            t[r][c4 * 4 + 3] = fmaxf(f.w, 0.f);
        }
        __syncthreads();
        #pragma unroll
        for (int j = 0; j < 4; ++j) {
            int c  = j * 256 + tid;
            int d  = c >> 3;
            int c8 = c & 7;
            ushort4 o;
            o.x = bf16b(t[c8 * 4 + 0][d]);
            o.y = bf16b(t[c8 * 4 + 1][d]);
            o.z = bf16b(t[c8 * 4 + 2][d]);
            o.w = bf16b(t[c8 * 4 + 3][d]);
            *(ushort4*)(dst + (size_t)d * Lc + l0 + c8 * 4) = o;
        }
    } else {
        int m = bid - 6144;
        int wv = tid >> 6, lane = tid & 63;
        #pragma unroll
        for (int i = 0; i < 16; ++i) {
            int wid = m * 64 + wv * 16 + i;
            int b = wid >> 16, l = (wid >> 5) & 2047, ktw = wid & 31;
            int mm = mask[(((size_t)(b * 2048 + l)) << 11) + ktw * 64 + lane];
            unsigned long long bal = __ballot(mm != 0);
            if (lane == 0) mb[(((size_t)(b * 32 + ktw)) << 11) + l] = bal;
        }
    }
}

// ---- main: 8-wave single-block, QUAD-buffered (1 barrier/tile, distance-2 WAR
// guarantee), XCD-localized grid ----
__global__ __launch_bounds__(512, 2) void rev_attn_kernel(
    const float* __restrict__ q,
    const unsigned short* __restrict__ kb,
    const unsigned short* __restrict__ vt,
    const unsigned long long* __restrict__ mb,
    float* __restrict__ out)
{
    // LDS: Kbuf[4] @ 0..49152, Vbuf[4] @ 65536..114688 (128 KB total);
    // epilogue scratch aliases base (drained via vmcnt(0) first)
    __shared__ __align__(16) char smem[131072];

    const int tid  = threadIdx.x;
    const int w    = tid >> 6;          // 0..7
    const int lane = tid & 63;
    const int l31  = lane & 31;
    const int hi   = lane >> 5;
    const int bh   = blockIdx.x;        // flat-id % 8 == bh % 8 -> same-bh blocks share an XCD
    const int b    = bh >> 4;
    const int qb   = blockIdx.y * QBLK + w * 32;
    const int qrow = qb + l31;

    const float*              qp = q  + (size_t)bh * Lc * Dc;
    const unsigned short*     kp = kb + (size_t)bh * Lc * Dc;
    const unsigned short*     vp = vt + (size_t)bh * Dc * Lc;
    const unsigned long long* mp = mb + ((size_t)b << 16) + qrow;   // [32 ktw][2048 l]
    float*                    op = out + (size_t)bh * Lc * Dc;

    // ---- Q B-frags (log2-domain pre-scale): lane holds Q[qrow][c*16 + hi*8 + j] ----
    short8 qf[8];
    {
        const float* qr0 = qp + (size_t)qrow * Dc + hi * 8;
        #pragma unroll
        for (int c = 0; c < 8; ++c) {
            const float* src = qr0 + c * 16;
            #pragma unroll
            for (int j = 0; j < 8; ++j)
                qf[c][j] = (short)bf16b(src[j] * SCL2);
        }
    }

    // ---- compact hoisted LDS byte-offsets (row-B = +8192 literal; swz invariant) ----
    unsigned koff[8], voff[8];
    #pragma unroll
    for (int c = 0; c < 8; ++c)
        koff[c] = (unsigned)(l31 * 256 + ((((c << 1) | hi) ^ (l31 & 15)) << 4));
    #pragma unroll
    for (int hs = 0; hs < 2; ++hs)
        #pragma unroll
        for (int ks = 0; ks < 4; ++ks)
            voff[hs * 4 + ks] = (unsigned)(l31 * 256 +
                ((((hs << 3) | (ks << 1) | hi) ^ (l31 & 15)) << 4));

    // ---- loop-carried staging pointers (512 threads -> 2 K + 2 V chunks each) ----
    const unsigned short *kp0, *kp1, *vp0, *vp1;
    {
        #define INITP(P, KP, VP) {                                   \
            int l   = (P) * 512 + tid;                               \
            int row = l >> 4, cl = l & 15;                           \
            int s_  = cl ^ (row & 15);                               \
            KP = kp + (size_t)row * Dc + s_ * 8;                     \
            int ds_ = row + ((s_ >> 3) << 6);                        \
            int ko_ = (s_ & 7) * 8;                                  \
            VP = vp + (size_t)ds_ * Lc + ko_;                        \
        }
        INITP(0, kp0, vp0) INITP(1, kp1, vp1)
        #undef INITP
    }

    f32x16 o0 = (f32x16)0.f, o1 = (f32x16)0.f, o2 = (f32x16)0.f, o3 = (f32x16)0.f;
    f32x16 lacc = (f32x16)0.f;          // denominator via MFMA(ones, P)
    short8 ones;
    #pragma unroll
    for (int j = 0; j < 8; ++j) ones[j] = (short)0x3F80;   // bf16 1.0

    // stage current pointers into buf (0..3), then advance (late advances read up to
    // 2 tiles OOB into the adjacent ws regions -- valid memory, never consumed)
    #define STAGE(buf) do {                                                        \
        char* Kdst = smem + (buf) * 16384;                                         \
        char* Vdst = smem + 65536 + (buf) * 16384;                                 \
        gload_lds16(kp0, Kdst + tid * 16);                                         \
        gload_lds16(vp0, Vdst + tid * 16);                                         \
        gload_lds16(kp1, Kdst + 8192 + tid * 16);                                  \
        gload_lds16(vp1, Vdst + 8192 + tid * 16);                                  \
        kp0 += KBLK * Dc; kp1 += KBLK * Dc;                                        \
        vp0 += KBLK;      vp1 += KBLK;                                             \
    } while (0)

    // slice: 8 elems of SV -> masked exp2 -> packed bf16 A-frag (cvt_pk + permlane32_swap)
    #define MK_SLICE(PA, SV, J0, CS0, MREG) do {                                   \
        float e0 = ((MREG >> (CS0 + 0)) & 1u)  ? __builtin_amdgcn_exp2f(SV[J0 + 0]) : 0.f; \
        float e1 = ((MREG >> (CS0 + 1)) & 1u)  ? __builtin_amdgcn_exp2f(SV[J0 + 1]) : 0.f; \
        float e2 = ((MREG >> (CS0 + 2)) & 1u)  ? __builtin_amdgcn_exp2f(SV[J0 + 2]) : 0.f; \
        float e3 = ((MREG >> (CS0 + 3)) & 1u)  ? __builtin_amdgcn_exp2f(SV[J0 + 3]) : 0.f; \
        float e4 = ((MREG >> (CS0 + 8)) & 1u)  ? __builtin_amdgcn_exp2f(SV[J0 + 4]) : 0.f; \
        float e5 = ((MREG >> (CS0 + 9)) & 1u)  ? __builtin_amdgcn_exp2f(SV[J0 + 5]) : 0.f; \
        float e6 = ((MREG >> (CS0 + 10)) & 1u) ? __builtin_amdgcn_exp2f(SV[J0 + 6]) : 0.f; \
        float e7 = ((MREG >> (CS0 + 11)) & 1u) ? __builtin_amdgcn_exp2f(SV[J0 + 7]) : 0.f; \
        unsigned a_ = cvtpk(e0, e1), a2_ = cvtpk(e2, e3);                          \
        unsigned b_ = cvtpk(e4, e5), b2_ = cvtpk(e6, e7);                          \
        asm volatile("v_permlane32_swap_b32 %0, %1" : "+v"(a_),  "+v"(b_));        \
        asm volatile("v_permlane32_swap_b32 %0, %1" : "+v"(a2_), "+v"(b2_));       \
        union { unsigned u[4]; short8 v8; } tu_;                                   \
        tu_.u[0] = a_; tu_.u[1] = a2_; tu_.u[2] = b_; tu_.u[3] = b2_;              \
        PA = tu_.v8;                                                               \
    } while (0)

    // PV for one k-slice: lacc + 4 d-tiles (offsets hoisted; +8192 = row-B literal)
    #define PV_SLICE(PA, KS) do {                                                  \
        __builtin_amdgcn_s_setprio(1);                                             \
        lacc = __builtin_amdgcn_mfma_f32_32x32x16_bf16(ones, PA, lacc, 0, 0, 0);   \
        short8 vfa = *(const short8*)(Vb + voff[KS]);                              \
        o0 = __builtin_amdgcn_mfma_f32_32x32x16_bf16(vfa, PA, o0, 0, 0, 0);        \
        short8 vfb = *(const short8*)(Vb + voff[KS] + 8192);                       \
        o1 = __builtin_amdgcn_mfma_f32_32x32x16_bf16(vfb, PA, o1, 0, 0, 0);        \
        short8 vfc = *(const short8*)(Vb + voff[4 + KS]);                          \
        o2 = __builtin_amdgcn_mfma_f32_32x32x16_bf16(vfc, PA, o2, 0, 0, 0);        \
        short8 vfd = *(const short8*)(Vb + voff[4 + KS] + 8192);                   \
        o3 = __builtin_amdgcn_mfma_f32_32x32x16_bf16(vfd, PA, o3, 0, 0, 0);        \
        __builtin_amdgcn_s_setprio(0);                                             \
    } while (0)

    // ---- prologue: stage tiles 0,1 + their mask words; no wait (uniform vmcnt below) ----
    STAGE(0);
    unsigned long long mw_c = mp[0];                 // tile 0
    STAGE(1);
    unsigned long long mw_n = mp[(size_t)1 << 11];   // tile 1

    int cur = 0;
    for (int kt = 0; kt < Lc; kt += KBLK) {
        // stage tile T+2 into buf (cur+2)&3 -- overwrites tile T-2's buffer, whose
        // last readers finished before arriving at barrier(T-1), which we have passed
        STAGE((cur + 2) & 3);
        int tn = (kt >> 6) + 2; if (tn > 31) tn = 31;
        unsigned long long mw_nn = mp[(size_t)tn << 11];

        // tile T (buf cur, staged 2 iters ago) ready: 2 newer iters' 5 loads in flight
        asm volatile("s_waitcnt vmcnt(10)" ::: "memory");
        __builtin_amdgcn_s_barrier();
        __builtin_amdgcn_sched_barrier(0);

        const char* Kb = smem + cur * 16384;
        const char* Vb = smem + 65536 + cur * 16384;

        // ---- QK^T (swapped): S^T[k][q], col=q=l31 ----
        f32x16 s0 = (f32x16)0.f, s1 = (f32x16)0.f;
        __builtin_amdgcn_s_setprio(1);
        #pragma unroll
        for (int c = 0; c < 8; ++c) {
            short8 kf0 = *(const short8*)(Kb + koff[c]);
            s0 = __builtin_amdgcn_mfma_f32_32x32x16_bf16(kf0, qf[c], s0, 0, 0, 0);
            short8 kf1 = *(const short8*)(Kb + koff[c] + 8192);
            s1 = __builtin_amdgcn_mfma_f32_32x32x16_bf16(kf1, qf[c], s1, 0, 0, 0);
        }
        __builtin_amdgcn_s_setprio(0);

        unsigned m0 = ((unsigned)(mw_c & 0xffffffffull)) >> (4 * hi);
        unsigned m1 = ((unsigned)(mw_c >> 32)) >> (4 * hi);

        // ---- sm-split: per k-slice {softmax 8 elems} then {5 MFMAs} ----
        short8 pa;
        MK_SLICE(pa, s0, 0, 0,  m0);  PV_SLICE(pa, 0);
        MK_SLICE(pa, s0, 8, 16, m0);  PV_SLICE(pa, 1);
        MK_SLICE(pa, s1, 0, 0,  m1);  PV_SLICE(pa, 2);
        MK_SLICE(pa, s1, 8, 16, m1);  PV_SLICE(pa, 3);

        // NO second barrier: quad-buffer distance-2 makes the WAR ordering follow
        // from barrier(T-1) alone. Rotate state.
        mw_c = mw_n; mw_n = mw_nn;
        cur = (cur + 1) & 3;
    }

    // ---- epilogue: drain in-flight OOB stage loads (they target bufs aliased by
    // scratch), then O^T -> LDS transpose -> coalesced float4 stores ----
    asm volatile("s_waitcnt vmcnt(0)" ::: "memory");
    __syncthreads();
    float inv = 1.0f / lacc[0];         // all regs identical (A = ones); col=q=l31
    float* scr = (float*)(smem + w * 4608);
    const int qq = lane >> 1;
    const int dh = (lane & 1) * 16;
    #pragma unroll
    for (int dt = 0; dt < 4; ++dt) {
        const f32x16& oo = (dt == 0) ? o0 : (dt == 1) ? o1 : (dt == 2) ? o2 : o3;
        #pragma unroll
        for (int r = 0; r < 16; ++r) {
            int drow = (r & 3) + 8 * (r >> 2) + 4 * hi;
            scr[drow * 36 + l31] = oo[r] * inv;
        }
        asm volatile("s_waitcnt lgkmcnt(0)" ::: "memory");
        __builtin_amdgcn_sched_barrier(0);
        float t[16];
        #pragma unroll
        for (int c2 = 0; c2 < 16; ++c2)
            t[c2] = scr[(dh + c2) * 36 + qq];
        asm volatile("s_waitcnt lgkmcnt(0)" ::: "memory");
        __builtin_amdgcn_sched_barrier(0);
        float* od = op + (size_t)(qb + qq) * Dc + dt * 32 + dh;
        #pragma unroll
        for (int c2 = 0; c2 < 4; ++c2) {
            float4 f4; f4.x = t[c2*4]; f4.y = t[c2*4+1]; f4.z = t[c2*4+2]; f4.w = t[c2*4+3];
            *(float4*)(od + c2 * 4) = f4;
        }
    }
}

extern "C" void kernel_launch(void* const* d_in, const int* in_sizes, int n_in,
                              void* d_out, int out_size, void* d_ws, size_t ws_size,
                              hipStream_t stream) {
    const float* q    = (const float*)d_in[0];
    const float* k    = (const float*)d_in[1];
    const float* v    = (const float*)d_in[2];
    const int*   mask = (const int*)d_in[3];
    float*       out  = (float*)d_out;

    char* ws = (char*)d_ws;
    unsigned short*     kb  = (unsigned short*)(ws + KB_OFF);
    unsigned short*     vt  = (unsigned short*)(ws + VT_OFF);
    unsigned long long* mbp = (unsigned long long*)(ws + MB_OFF);

    hipLaunchKernelGGL(prepass_kernel, dim3(8192), dim3(256), 0, stream, k, v, mask, kb, vt, mbp);
    // grid (bh, qx): flat id % 8 == bh % 8 -> same-bh q-blocks share one XCD's L2
    hipLaunchKernelGGL(rev_attn_kernel, dim3(Bc * Hc, Lc / QBLK), dim3(512), 0, stream,
                       q, kb, vt, mbp, out);
}